// Round 8
// baseline (287.318 us; speedup 1.0000x reference)
//
#include <hip/hip_runtime.h>
#include <math.h>

#define N_TOK 16384
#define DM    2048
#define NE    64
#define TOPK  4

#define OFF_TI  0
#define OFF_TS  (N_TOK * TOPK)
#define OFF_SC  (2 * N_TOK * TOPK)
#define OFF_AUX (2 * N_TOK * TOPK + N_TOK * NE)

// ---------------- MFMA path ----------------
#define MTPB  64             // tokens per block -> grid 256 = 1 block/CU
#define RW    256            // dims per staged round (8 waves x 32)
#define NRND  (DM / RW)      // 8
#define PLN_F (MTPB * RW)    // 16384 f32 per u buffer (64 KB)

#define EH_OFF   1024                      // byte offset of packed Eh in ws
#define ET_ELEMS ((size_t)NE * DM)         // 131072 bf16 per table
#define WS_NEED  (EH_OFF + 4 * ET_ELEMS)   // 525,312 B

typedef short s8v __attribute__((ext_vector_type(8)));   // 8 bf16 = 4 VGPR
typedef float f4v __attribute__((ext_vector_type(4)));

__device__ __forceinline__ unsigned short bf16_rne(float x) {
  unsigned int b = __float_as_uint(x);
  b += 0x7FFFu + ((b >> 16) & 1u);
  return (unsigned short)(b >> 16);
}

// f32x8 -> hi/lo bf16x8 split (exact: u = hi + lo + ~2^-17). Same math as
// all passing rounds; now applied at LDS-read time instead of stage time.
__device__ __forceinline__ void cvt8(float4 a, float4 b, s8v* hi, s8v* lo) {
  union { s8v v; unsigned u[4]; } H, L;
  const float f0[4] = {a.x, a.z, b.x, b.z};
  const float f1[4] = {a.y, a.w, b.y, b.w};
#pragma unroll
  for (int i = 0; i < 4; ++i) {
    const unsigned short h0 = bf16_rne(f0[i]), h1 = bf16_rne(f1[i]);
    const float l0 = f0[i] - __uint_as_float((unsigned)h0 << 16);
    const float l1 = f1[i] - __uint_as_float((unsigned)h1 << 16);
    H.u[i] = (unsigned)h0 | ((unsigned)h1 << 16);
    L.u[i] = (unsigned)bf16_rne(l0) | ((unsigned)bf16_rne(l1) << 16);
  }
  *hi = H.v; *lo = L.v;
}

// E[2048][64] f32 -> PACKED B-fragment layout (R6/R7-verified), hi/lo bf16:
//   EP[pk][j][lane][q]: expert = j*16+(lane&15), k = pk*32+(lane>>4)*8+q.
// Also zeroes ws[0..127] (per-expert partials + ticket counter).
__global__ __launch_bounds__(256) void router_prep(
    const float* __restrict__ E, unsigned short* __restrict__ eh,
    unsigned short* __restrict__ el, float* __restrict__ ws)
{
  __shared__ float t[32][65];
  const int tid = threadIdx.x;
  if (blockIdx.x == 0 && tid < 128) ws[tid] = 0.f;
  const int k0  = blockIdx.x * 32;          // = pk * 32
#pragma unroll
  for (int i = 0; i < 2; ++i) {
    const int fi = i * 256 + tid;
    const int kk = fi >> 4, ee = (fi & 15) * 4;
    const float4 v = *(const float4*)(E + (size_t)(k0 + kk) * NE + ee);
    t[kk][ee] = v.x; t[kk][ee + 1] = v.y; t[kk][ee + 2] = v.z; t[kk][ee + 3] = v.w;
  }
  __syncthreads();
  const int j    = tid >> 6;                // expert group
  const int lane = tid & 63;                // B-lane
  const int ex   = j * 16 + (lane & 15);    // expert
  const int kb   = (lane >> 4) * 8;         // k offset within block
  unsigned int hw[4], lw[4];
#pragma unroll
  for (int p = 0; p < 4; ++p) {
    unsigned short h[2], l[2];
#pragma unroll
    for (int q = 0; q < 2; ++q) {
      const float x = t[kb + p * 2 + q][ex];
      h[q] = bf16_rne(x);
      l[q] = bf16_rne(x - __uint_as_float((unsigned)h[q] << 16));
    }
    hw[p] = (unsigned)h[0] | ((unsigned)h[1] << 16);
    lw[p] = (unsigned)l[0] | ((unsigned)l[1] << 16);
  }
  const size_t o = (size_t)blockIdx.x * 2048 + j * 512 + lane * 8;
  *(uint4*)(eh + o) = make_uint4(hw[0], hw[1], hw[2], hw[3]);
  *(uint4*)(el + o) = make_uint4(lw[0], lw[1], lw[2], lw[3]);
}

// 512 thr = 8 waves, 64 tokens/block, grid 256 (1 block/CU, 2 waves/SIMD).
// R7 diagnosis: time = ~300K cyc baseline + 52cyc x E-instr. Baseline =
// Little's law on u staging (4 waves x 8x16B in flight, vmcnt-drained each
// half-round -> ~1 B/cyc/CU vs 512KB/CU to move). Fix: global_load_lds
// (width 16) staging — no VGPR round-trip, deep HW queue, loads in flight
// across the whole compute phase; u hits its BW floor.
// Wave w owns pk = r*8 + w -> E-instr/CU stays 512 (R7's win kept).
// u LDS is linear f32 [64 tok][256] (global_load_lds writes base+lane*16B);
// bank conflicts on A-frag reads fixed by PRE-SWIZZLED SOURCE: stage lane l
// of row-instr i_ loads granule l^i_, reads apply g^(row&7) (self-inverse).
// bf16 hi/lo split (bit-identical RNE math) moved to LDS-read side.
#define STAGE(buf, r) do { _Pragma("unroll") \
  for (int i_ = 0; i_ < 8; ++i_) { \
    const float* gp_ = ub0 + (size_t)i_ * DM + (size_t)(r) * RW + ((lane ^ i_) << 2); \
    float* lp_ = shf + (size_t)(buf) * PLN_F + (w * 8 + i_) * RW; \
    __builtin_amdgcn_global_load_lds( \
        (const __attribute__((address_space(1))) unsigned int*)gp_, \
        (__attribute__((address_space(3))) unsigned int*)lp_, 16, 0, 0); \
  } } while (0)

#define COMPUTE(r, buf) do { \
    const float* bp_ = shf + (size_t)(buf) * PLN_F; \
    s8v ah_[4], al_[4]; \
    _Pragma("unroll") for (int tt_ = 0; tt_ < 4; ++tt_) { \
      const float* rb_ = bp_ + (tt_ * 16 + lm) * RW; \
      const int ga_ = (w * 8 + lk * 2) ^ (lm & 7); \
      const float4 fa_ = *(const float4*)(rb_ + ga_ * 4); \
      const float4 fb_ = *(const float4*)(rb_ + (ga_ ^ 1) * 4); \
      cvt8(fa_, fb_, &ah_[tt_], &al_[tt_]); \
    } \
    const size_t pb_ = (size_t)((r) * 8 + w) * 2048 + lane * 8; \
    _Pragma("unroll") for (int j_ = 0; j_ < 4; ++j_) { \
      const s8v bh_ = *(const s8v*)&eh[pb_ + j_ * 512]; \
      const s8v bl_ = *(const s8v*)&el[pb_ + j_ * 512]; \
      _Pragma("unroll") for (int tt_ = 0; tt_ < 4; ++tt_) { \
        acc[tt_][j_] = __builtin_amdgcn_mfma_f32_16x16x32_bf16(ah_[tt_], bh_, acc[tt_][j_], 0, 0, 0); \
        acc[tt_][j_] = __builtin_amdgcn_mfma_f32_16x16x32_bf16(ah_[tt_], bl_, acc[tt_][j_], 0, 0, 0); \
        acc[tt_][j_] = __builtin_amdgcn_mfma_f32_16x16x32_bf16(al_[tt_], bh_, acc[tt_][j_], 0, 0, 0); \
        acc[tt_][j_] = __builtin_amdgcn_mfma_f32_16x16x32_bf16(al_[tt_], bl_, acc[tt_][j_], 0, 0, 0); \
      } } } while (0)

__global__ __launch_bounds__(512, 1) void router_main_mfma(
    const float* __restrict__ u, const unsigned short* __restrict__ eh,
    const unsigned short* __restrict__ el, const float* __restrict__ bias,
    float* __restrict__ out, float* __restrict__ ws)
{
  __shared__ __align__(16) float shf[2 * PLN_F];   // 131,072 B

  const int tid  = threadIdx.x;
  const int lane = tid & 63;
  const int w    = __builtin_amdgcn_readfirstlane(tid >> 6);  // wave = K-slice
  const int lm   = lane & 15;          // A: token row
  const int lk   = lane >> 4;          // k-group (8 f32 each)
  const int tok0 = blockIdx.x * MTPB;

  // staging base: wave w stages token rows w*8..+7 (1KB each, linear LDS)
  const float* ub0 = u + (size_t)(tok0 + w * 8) * DM;

  f4v acc[4][4];
#pragma unroll
  for (int t = 0; t < 4; ++t)
#pragma unroll
    for (int j = 0; j < 4; ++j) acc[t][j] = (f4v){0.f, 0.f, 0.f, 0.f};

  STAGE(0, 0);
  __syncthreads();                     // drains vmcnt: buf0 = round 0

  int cur = 0;
  for (int r = 0; r < NRND; ++r) {
    if (r + 1 < NRND) STAGE(cur ^ 1, r + 1);   // issue-early, in flight across compute
    COMPUTE(r, cur);
    __syncthreads();                           // one barrier+drain per round
    cur ^= 1;
  }

  // ---- 8 K-partials: fin[4][64 tok][68] (aliases shf, 69.6 KB) ----
  // D frags: col=lane&15 <-> expert(j*16+lm), row=lk*4+q <-> token (tt*16+).
  float* fin = shf;
  if (w < 4) {
#pragma unroll
    for (int t = 0; t < 4; ++t)
#pragma unroll
      for (int j = 0; j < 4; ++j)
#pragma unroll
        for (int q = 0; q < 4; ++q)
          fin[w * (64 * 68) + (t * 16 + lk * 4 + q) * 68 + j * 16 + lm] = acc[t][j][q];
  }
  __syncthreads();
  if (w >= 4) {
#pragma unroll
    for (int t = 0; t < 4; ++t)
#pragma unroll
      for (int j = 0; j < 4; ++j)
#pragma unroll
        for (int q = 0; q < 4; ++q)
          fin[(w - 4) * (64 * 68) + (t * 16 + lk * 4 + q) * 68 + j * 16 + lm] += acc[t][j][q];
  }
  __syncthreads();

  // ---- epilogue: wave w -> tokens w*8..+7, lane = expert (verified) ----
  const float be = bias[lane];
  float asum = 0.f;
  for (int tt = 0; tt < 8; ++tt) {
    const int t = w * 8 + tt;
    float x = fin[t * 68 + lane] + fin[4352 + t * 68 + lane]
            + fin[2 * 4352 + t * 68 + lane] + fin[3 * 4352 + t * 68 + lane] + be;

    float m = x;
#pragma unroll
    for (int off = 32; off > 0; off >>= 1) m = fmaxf(m, __shfl_xor(m, off));
    float p = expf(x - m);
    float s = p;
#pragma unroll
    for (int off = 32; off > 0; off >>= 1) s += __shfl_xor(s, off);
    float sc = p / s;

    out[OFF_SC + (size_t)(tok0 + t) * NE + lane] = sc;
    asum += sc;

    float v = sc;
#pragma unroll
    for (int k = 0; k < TOPK; ++k) {
      float bv = v;
      int   bi = lane;
#pragma unroll
      for (int off = 32; off > 0; off >>= 1) {
        float ov = __shfl_xor(bv, off);
        int   oi = __shfl_xor(bi, off);
        if (ov > bv || (ov == bv && oi < bi)) { bv = ov; bi = oi; }
      }
      if (lane == k) {
        out[OFF_TI + (size_t)(tok0 + t) * TOPK + k] = (float)bi;
        out[OFF_TS + (size_t)(tok0 + t) * TOPK + k] = bv;
      }
      if (lane == bi) v = -INFINITY;
    }
  }
  atomicAdd(&ws[lane], asum);   // per-expert partial for aux loss

  // ---- folded aux: last block to finish reduces ws (device-scope ticket) ----
  __threadfence();
  __syncthreads();
  unsigned* flg = (unsigned*)shf;
  if (tid == 0) {
    const unsigned t = atomicAdd((unsigned*)&ws[NE], 1u);   // ws[64] = counter
    flg[30000] = (t == (unsigned)(gridDim.x - 1)) ? 1u : 0u;
  }
  __syncthreads();
  if (flg[30000] && tid < 64) {
    const float mv = atomicAdd(&ws[tid], 0.f) * (1.0f / N_TOK);  // coherent read
    float v = mv * mv;
#pragma unroll
    for (int off = 32; off > 0; off >>= 1) v += __shfl_xor(v, off);
    if (tid == 0) out[OFF_AUX] = v * (float)NE;
  }
}

// ---------------- fallback (ws too small): proven R1 kernel ----------------
#define TPB     64
#define FB_DC   32
#define FB_NCH  (1024 / FB_DC)
#define FB_LSTR 68
#define FB_UB   (TPB * FB_LSTR)
#define FB_EOFF (2 * FB_UB)
#define FB_EB   (2 * FB_DC * NE)

__global__ __launch_bounds__(1024, 4) void router_main_fb(
    const float* __restrict__ u, const float* __restrict__ E,
    const float* __restrict__ bias, float* __restrict__ out,
    float* __restrict__ ws)
{
  __shared__ float smem[FB_EOFF + 2 * FB_EB];

  const int tid  = threadIdx.x;
  const int lane = tid & 63;
  const int wid  = __builtin_amdgcn_readfirstlane(tid >> 6);
  const int eg   = wid & 7;
  const int kh   = wid >> 3;
  const int tok0 = blockIdx.x * TPB;

  const int stok  = tid >> 4;
  const int sdseg = tid & 15;
  const int skh   = sdseg >> 3;
  const int sdsub = (sdseg & 7) * 4;
  const float* sgbase = u + (size_t)(tok0 + stok) * DM + skh * 1024 + sdsub;
  float* swp = smem + stok * FB_LSTR + sdseg * 4;

  const int eq  = tid & 511;
  const int ekh = tid >> 9;
  const float* egbase = E + (size_t)ekh * 1024 * NE + eq * 4;
  float* ewp = smem + FB_EOFF + ekh * (FB_DC * NE) + eq * 4;

  float acc[8];
#pragma unroll
  for (int j = 0; j < 8; ++j) acc[j] = 0.f;

  float4 pf[3];
  pf[0] = *(const float4*)(sgbase + 0 * FB_DC);
  pf[1] = *(const float4*)(sgbase + 1 * FB_DC);
  pf[2] = *(const float4*)(sgbase + 2 * FB_DC);
  float4 epf = *(const float4*)(egbase + 0 * (FB_DC * NE));
  *(float4*)(swp + 0) = pf[0];
  *(float4*)(ewp + 0) = epf;
  epf = *(const float4*)(egbase + 1 * (FB_DC * NE));
  __syncthreads();

  for (int c = 0; c < FB_NCH; ++c) {
    if (c + 1 < FB_NCH) {
      *(float4*)(swp + ((c + 1) & 1) * FB_UB) = pf[(c + 1) % 3];
      *(float4*)(ewp + ((c + 1) & 1) * FB_EB) = epf;
    }
    if (c + 2 < FB_NCH)
      epf = *(const float4*)(egbase + (c + 2) * (FB_DC * NE));
    if (c + 3 < FB_NCH)
      pf[c % 3] = *(const float4*)(sgbase + (c + 3) * FB_DC);

    const float* sb = smem + (c & 1) * FB_UB + lane * FB_LSTR + kh * FB_DC;
    const float* eb = smem + FB_EOFF + (c & 1) * FB_EB + kh * (FB_DC * NE) + eg * 8;
#pragma unroll
    for (int s = 0; s < 8; ++s) {
      float4 uf = *(const float4*)(sb + s * 4);
#pragma unroll
      for (int dd = 0; dd < 4; ++dd) {
        const float* er = eb + (s * 4 + dd) * NE;
        float4 e0 = *(const float4*)(er);
        float4 e1 = *(const float4*)(er + 4);
        const float uv = (&uf.x)[dd];
        acc[0] = fmaf(e0.x, uv, acc[0]);
        acc[1] = fmaf(e0.y, uv, acc[1]);
        acc[2] = fmaf(e0.z, uv, acc[2]);
        acc[3] = fmaf(e0.w, uv, acc[3]);
        acc[4] = fmaf(e1.x, uv, acc[4]);
        acc[5] = fmaf(e1.y, uv, acc[5]);
        acc[6] = fmaf(e1.z, uv, acc[6]);
        acc[7] = fmaf(e1.w, uv, acc[7]);
      }
    }
    __syncthreads();
  }

  float* fin = smem;
  if (kh == 0) {
#pragma unroll
    for (int j = 0; j < 8; ++j) fin[lane * 65 + eg * 8 + j] = acc[j];
  }
  __syncthreads();
  if (kh == 1) {
#pragma unroll
    for (int j = 0; j < 8; ++j) fin[lane * 65 + eg * 8 + j] += acc[j];
  }
  __syncthreads();

  const float be = bias[lane];
  float asum = 0.f;
#pragma unroll
  for (int tt = 0; tt < 4; ++tt) {
    const int t = wid * 4 + tt;
    float x = fin[t * 65 + lane] + be;

    float m = x;
#pragma unroll
    for (int off = 32; off > 0; off >>= 1) m = fmaxf(m, __shfl_xor(m, off));
    float p = expf(x - m);
    float s = p;
#pragma unroll
    for (int off = 32; off > 0; off >>= 1) s += __shfl_xor(s, off);
    float sc = p / s;

    out[OFF_SC + (size_t)(tok0 + t) * NE + lane] = sc;
    asum += sc;

    float v = sc;
#pragma unroll
    for (int k = 0; k < TOPK; ++k) {
      float bv = v;
      int   bi = lane;
#pragma unroll
      for (int off = 32; off > 0; off >>= 1) {
        float ov = __shfl_xor(bv, off);
        int   oi = __shfl_xor(bi, off);
        if (ov > bv || (ov == bv && oi < bi)) { bv = ov; bi = oi; }
      }
      if (lane == k) {
        out[OFF_TI + (size_t)(tok0 + t) * TOPK + k] = (float)bi;
        out[OFF_TS + (size_t)(tok0 + t) * TOPK + k] = bv;
      }
      if (lane == bi) v = -INFINITY;
    }
  }
  atomicAdd(&ws[lane], asum);
}

__global__ void router_aux(const float* __restrict__ ws, float* __restrict__ out)
{
  const int lane = threadIdx.x & 63;
  float m = ws[lane] * (1.0f / N_TOK);
  float v = m * m;
#pragma unroll
  for (int off = 32; off > 0; off >>= 1) v += __shfl_xor(v, off);
  if (lane == 0) out[OFF_AUX] = v * (float)NE;
}

extern "C" void kernel_launch(void* const* d_in, const int* in_sizes, int n_in,
                              void* d_out, int out_size, void* d_ws, size_t ws_size,
                              hipStream_t stream) {
  const float* u    = (const float*)d_in[0];
  const float* E    = (const float*)d_in[1];
  const float* bias = (const float*)d_in[2];
  float* out = (float*)d_out;
  float* ws  = (float*)d_ws;

  if (ws_size >= WS_NEED) {
    unsigned short* eh = (unsigned short*)((char*)ws + EH_OFF);
    unsigned short* el = eh + ET_ELEMS;
    router_prep<<<DM / 32, 256, 0, stream>>>(E, eh, el, ws);
    router_main_mfma<<<N_TOK / MTPB, 512, 0, stream>>>(u, eh, el, bias, out, ws);
  } else {
    hipMemsetAsync(ws, 0, NE * sizeof(float), stream);
    router_main_fb<<<N_TOK / TPB, 1024, 0, stream>>>(u, E, bias, out, ws);
    router_aux<<<1, 64, 0, stream>>>(ws, out);
  }
}